// Round 9
// baseline (1495.402 us; speedup 1.0000x reference)
//
#include <hip/hip_runtime.h>
#include <math.h>

#define NN 50000
#define EN 200000
#define CC 4
#define HH 128
#define GG 64
#define LDSA 136   // padded stride for pool-variant tile
#define LDSF 132   // f32 stride for fused-pool tile

typedef __attribute__((ext_vector_type(8))) short bs8;
typedef __attribute__((ext_vector_type(4))) float f32x4;
typedef __attribute__((ext_vector_type(2))) float f32x2;

__device__ __forceinline__ unsigned short f2bf(float f) {
  unsigned int u = __float_as_uint(f);
  u += 0x7FFFu + ((u >> 16) & 1u);
  return (unsigned short)(u >> 16);
}
__device__ __forceinline__ float bf2f(unsigned short h) {
  return __uint_as_float(((unsigned int)h) << 16);
}
// fast erf-GELU: A&S 7.1.26 minimax (|erf err| ~1.5e-7) + hw rcp/exp
__device__ __forceinline__ float gelu_f(float x) {
  float z = fabsf(x) * 0.7071067811865476f;
  float t = __builtin_amdgcn_rcpf(fmaf(0.3275911f, z, 1.0f));
  float poly = t * fmaf(t, fmaf(t, fmaf(t, fmaf(t, 1.061405429f, -1.453152027f),
                                        1.421413741f), -0.284496736f), 0.254829592f);
  float e = fmaf(-poly, __expf(-z * z), 1.0f);
  return 0.5f * x * (1.0f + copysignf(e, x));
}
// 2*gelu(x) — caller pre-folds the 0.5 into the edge mask
__device__ __forceinline__ float gelu2_f(float x) {
  float z = fabsf(x) * 0.7071067811865476f;
  float t = __builtin_amdgcn_rcpf(fmaf(0.3275911f, z, 1.0f));
  float poly = t * fmaf(t, fmaf(t, fmaf(t, fmaf(t, 1.061405429f, -1.453152027f),
                                        1.421413741f), -0.284496736f), 0.254829592f);
  float e = fmaf(-poly, __expf(-z * z), 1.0f);
  return x * (1.0f + copysignf(e, x));
}

// ---------------- CSR build ----------------
__global__ __launch_bounds__(256) void count_kernel(const int* __restrict__ dst,
                                                    int* __restrict__ counts) {
  int e = blockIdx.x * 256 + threadIdx.x;
  if (e < EN) atomicAdd(&counts[dst[e]], 1);
}

__global__ __launch_bounds__(256) void block_sum_kernel(const int* __restrict__ counts,
                                                        int* __restrict__ bsums) {
  int tid = threadIdx.x;
  int i = blockIdx.x * 256 + tid;
  int v = (i < NN) ? counts[i] : 0;
#pragma unroll
  for (int d = 1; d < 64; d <<= 1) v += __shfl_xor(v, d);
  __shared__ int ws4[4];
  if ((tid & 63) == 0) ws4[tid >> 6] = v;
  __syncthreads();
  if (tid == 0) bsums[blockIdx.x] = ws4[0] + ws4[1] + ws4[2] + ws4[3];
}

__global__ __launch_bounds__(256) void bsum_scan_kernel(const int* __restrict__ bsums,
                                                        int* __restrict__ boffs, int nb) {
  int tid = threadIdx.x, lane = tid & 63, wv = tid >> 6;
  int v = (tid < nb) ? bsums[tid] : 0;
  int s = v;
#pragma unroll
  for (int d = 1; d < 64; d <<= 1) { int t = __shfl_up(s, d); if (lane >= d) s += t; }
  __shared__ int wsum[4];
  if (lane == 63) wsum[wv] = s;
  __syncthreads();
  int pre = 0;
  for (int j = 0; j < wv; ++j) pre += wsum[j];
  if (tid < nb) boffs[tid] = pre + s - v;
}

__global__ __launch_bounds__(256) void block_scan_kernel(const int* __restrict__ counts,
                                                         const int* __restrict__ boffs,
                                                         int* __restrict__ offsets,
                                                         int* __restrict__ cursor) {
  int tid = threadIdx.x, lane = tid & 63, wv = tid >> 6;
  int i = blockIdx.x * 256 + tid;
  int v = (i < NN) ? counts[i] : 0;
  int s = v;
#pragma unroll
  for (int d = 1; d < 64; d <<= 1) { int t = __shfl_up(s, d); if (lane >= d) s += t; }
  __shared__ int wsum[4];
  if (lane == 63) wsum[wv] = s;
  __syncthreads();
  int pre = boffs[blockIdx.x];
  for (int j = 0; j < wv; ++j) pre += wsum[j];
  if (i < NN) { int e = pre + s - v; offsets[i] = e; cursor[i] = e; }
  if (i == 0) offsets[NN] = EN;
}

// fill: CSR-ordered side arrays. csr_esd[pos] = (edge, src, dst, 0) — one 16B load
// gives everything agg needs; emask_s[pos] = emask[0..3][e] sequential 16B.
__global__ __launch_bounds__(256) void fill_kernel(const int* __restrict__ dst,
                                                   const int* __restrict__ src,
                                                   const float* __restrict__ emask,
                                                   int* __restrict__ cursor,
                                                   int4* __restrict__ csr_esd,
                                                   float4* __restrict__ emask_s) {
  int e = blockIdx.x * 256 + threadIdx.x;
  if (e < EN) {
    int s = src[e];
    int d = dst[e];
    float m0 = emask[e];
    float m1 = emask[EN + e];
    float m2 = emask[2 * EN + e];
    float m3 = emask[3 * EN + e];
    int pos = atomicAdd(&cursor[d], 1);
    csr_esd[pos] = make_int4(e, s, d, 0);
    emask_s[pos] = make_float4(m0, m1, m2, m3);
  }
}

// ---------------- weight prep: transpose + hi/lo bf16 split ----------------------
__global__ __launch_bounds__(256) void prep_w_kernel(const float* __restrict__ W1,
                                                     const float* __restrict__ W2,
                                                     const float* __restrict__ Wm1,
                                                     const float* __restrict__ Wm2,
                                                     unsigned short* __restrict__ wts) {
  int m = blockIdx.x >> 6;
  int idx = (blockIdx.x & 63) * 256 + threadIdx.x;  // 0..16383
  const float* src = (m == 0) ? W1 : (m == 1) ? W1 + 16384 : (m == 2) ? W2
                     : (m == 3) ? W2 + 16384 : (m == 4) ? Wm1 : Wm2;
  unsigned short* dhi = wts + m * 32768;
  unsigned short* dlo = dhi + 16384;
  int n = idx >> 7, k = idx & 127;
  float v = src[k * HH + n];  // src [k][n] -> dst [n][k]
  unsigned short hi = f2bf(v);
  dhi[n * HH + k] = hi;
  dlo[n * HH + k] = f2bf(v - bf2f(hi));
}

// ---------------- bond encoder: 16 edges per block ----------------
__global__ __launch_bounds__(256) void ee_kernel(const float* __restrict__ eattr,
                                                 const float* __restrict__ Wbe,
                                                 const float* __restrict__ bbe,
                                                 float* __restrict__ ee) {
  __shared__ float Ws[16 * HH];
  __shared__ float Ea[16 * 16];
  int tid = threadIdx.x;
  int e0 = blockIdx.x * 16;
#pragma unroll
  for (int i = 0; i < 8; ++i) Ws[tid + i * 256] = Wbe[tid + i * 256];
  Ea[tid] = eattr[(size_t)e0 * 16 + tid];
  __syncthreads();
  int h = tid & 127, half = tid >> 7;
  float bb = bbe[h];
#pragma unroll
  for (int j = 0; j < 8; ++j) {
    int el = j * 2 + half;
    float acc = bb;
#pragma unroll
    for (int d = 0; d < 16; ++d) acc += Ea[el * 16 + d] * Ws[d * HH + h];
    ee[(size_t)(e0 + el) * HH + h] = acc;
  }
}

// ---------------- MLP helpers ----------------------------------------------------
__device__ __forceinline__ void loadW(const unsigned short* __restrict__ whi,
                                      const unsigned short* __restrict__ wlo,
                                      bs8 (&bh)[4][2], bs8 (&bl)[4][2],
                                      int ln, int quad, int wq) {
#pragma unroll
  for (int ks = 0; ks < 4; ++ks)
#pragma unroll
    for (int nt = 0; nt < 2; ++nt) {
      int wrow = ((wq * 2 + nt) * 16 + ln) * HH + ks * 32 + quad * 8;
      bh[ks][nt] = *(const bs8*)(whi + wrow);
      bl[ks][nt] = *(const bs8*)(wlo + wrow);
    }
}
__device__ __forceinline__ void zacc(f32x4 (&acc)[4][2]) {
#pragma unroll
  for (int mt = 0; mt < 4; ++mt)
#pragma unroll
    for (int nt = 0; nt < 2; ++nt)
#pragma unroll
      for (int r = 0; r < 4; ++r) acc[mt][nt][r] = 0.f;
}
// 3-term GEMM over XOR-swizzled 64xHH LDS tile with preloaded W frags
__device__ __forceinline__ void gemm3(const unsigned short* Ahi, const unsigned short* Alo,
                                      const bs8 (&bh)[4][2], const bs8 (&bl)[4][2],
                                      f32x4 (&acc)[4][2], int ln, int quad) {
#pragma unroll
  for (int ks = 0; ks < 4; ++ks) {
    bs8 ah[4], al[4];
    int sb = ((ks * 4 + quad) ^ ln) * 8;
#pragma unroll
    for (int mt = 0; mt < 4; ++mt) {
      ah[mt] = *(const bs8*)(Ahi + (mt * 16 + ln) * HH + sb);
      al[mt] = *(const bs8*)(Alo + (mt * 16 + ln) * HH + sb);
    }
#pragma unroll
    for (int nt = 0; nt < 2; ++nt)
#pragma unroll
      for (int mt = 0; mt < 4; ++mt) {
        acc[mt][nt] = __builtin_amdgcn_mfma_f32_16x16x32_bf16(al[mt], bh[ks][nt], acc[mt][nt], 0, 0, 0);
        acc[mt][nt] = __builtin_amdgcn_mfma_f32_16x16x32_bf16(ah[mt], bl[ks][nt], acc[mt][nt], 0, 0, 0);
        acc[mt][nt] = __builtin_amdgcn_mfma_f32_16x16x32_bf16(ah[mt], bh[ks][nt], acc[mt][nt], 0, 0, 0);
      }
  }
}
// t = gelu(acc+b) -> swizzled LDS hi/lo
__device__ __forceinline__ void tstage(unsigned short* Ahi, unsigned short* Alo,
                                       const float* __restrict__ bv, f32x4 (&acc)[4][2],
                                       int ln, int quad, int wq) {
#pragma unroll
  for (int nt = 0; nt < 2; ++nt) {
    int col = (wq * 2 + nt) * 16 + ln;
    int cb = col >> 3, co = col & 7;
    float bb = bv[col];
#pragma unroll
    for (int mt = 0; mt < 4; ++mt)
#pragma unroll
      for (int r = 0; r < 4; ++r) {
        float tv = gelu_f(acc[mt][nt][r] + bb);
        unsigned short th = f2bf(tv);
        int rr = mt * 16 + quad * 4 + r;
        int sof = rr * HH + (cb ^ (rr & 15)) * 8 + co;
        Ahi[sof] = th;
        Alo[sof] = f2bf(tv - bf2f(th));
      }
  }
}

// ---- agg phase, edge-parallel: all 4 waves stride the block's contiguous CSR edge
// span; per edge each lane computes 8 GELU terms (cols l, l+64 x 4 channels) and
// ds_add_f32's them into a 64x128 f32 LDS accumulator (2 lanes/bank = conflict-
// free; no loop-carried register deps -> deep VMEM overlap). The f32 acc exactly
// overlays the bf16 hi/lo tile; a register-staged in-place pass then converts
// acc + (1+eps)*x_self into the swizzled tile for the GEMM chain.
__device__ __forceinline__ void agg_phase(const float* __restrict__ x,
                                          const float* __restrict__ ee,
                                          const int* __restrict__ off,
                                          const int4* __restrict__ csr_esd,
                                          const float4* __restrict__ emask_s,
                                          float ep, int n0,
                                          unsigned short* AB16, int tid) {
  float* accf = (float*)AB16;
  unsigned short* Ahi = AB16;
  unsigned short* Alo = AB16 + 64 * HH;
  int lane = tid & 63, wq = tid >> 6;

  // zero the f32 accumulator
#pragma unroll
  for (int i = 0; i < 16; ++i)
    *(float2*)&accf[(i * 256 + tid) * 2] = make_float2(0.f, 0.f);
  __syncthreads();

  int beg = off[n0], end = off[n0 + 16];
  for (int t = beg + wq; t < end; t += 4) {
    int4 esd = csr_esd[t];                       // (e, src, dst, 0) sequential 16B
    float4 m = emask_s[t];                       // wave-uniform broadcast
    const float* eerow = ee + (size_t)esd.x * HH;
    float ee0 = eerow[lane];
    float ee1 = eerow[lane + 64];
    int dl = esd.z - n0;                         // local dst row 0..15
    float m0 = 0.5f * m.x, m1 = 0.5f * m.y, m2 = 0.5f * m.z, m3 = 0.5f * m.w;
    const float* x0r = x + ((size_t)0 * NN + esd.y) * HH;
    const float* x1r = x + ((size_t)1 * NN + esd.y) * HH;
    const float* x2r = x + ((size_t)2 * NN + esd.y) * HH;
    const float* x3r = x + ((size_t)3 * NN + esd.y) * HH;
    atomicAdd(&accf[(0 * 16 + dl) * HH + lane],      gelu2_f(x0r[lane] + ee0) * m0);
    atomicAdd(&accf[(0 * 16 + dl) * HH + lane + 64], gelu2_f(x0r[lane + 64] + ee1) * m0);
    atomicAdd(&accf[(1 * 16 + dl) * HH + lane],      gelu2_f(x1r[lane] + ee0) * m1);
    atomicAdd(&accf[(1 * 16 + dl) * HH + lane + 64], gelu2_f(x1r[lane + 64] + ee1) * m1);
    atomicAdd(&accf[(2 * 16 + dl) * HH + lane],      gelu2_f(x2r[lane] + ee0) * m2);
    atomicAdd(&accf[(2 * 16 + dl) * HH + lane + 64], gelu2_f(x2r[lane + 64] + ee1) * m2);
    atomicAdd(&accf[(3 * 16 + dl) * HH + lane],      gelu2_f(x3r[lane] + ee0) * m3);
    atomicAdd(&accf[(3 * 16 + dl) * HH + lane + 64], gelu2_f(x3r[lane + 64] + ee1) * m3);
  }
  __syncthreads();

  // in-place f32 -> bf16 hi/lo conversion: read ALL before writing ANY (overlay)
  float a0[16], a1[16];
#pragma unroll
  for (int i = 0; i < 16; ++i) {
    int idx = i * 256 + tid;          // 0..4095
    int rr = idx >> 6, cw = idx & 63;
    a0[i] = accf[rr * HH + cw];
    a1[i] = accf[rr * HH + cw + 64];
  }
  __syncthreads();
#pragma unroll
  for (int i = 0; i < 16; ++i) {
    int idx = i * 256 + tid;
    int rr = idx >> 6, cw = idx & 63;
    int c = rr >> 4, node = n0 + (rr & 15);
    const float* xrow = x + ((size_t)c * NN + node) * HH;
    float h0 = fmaf(ep, xrow[cw], a0[i]);
    float h1 = fmaf(ep, xrow[cw + 64], a1[i]);
    unsigned short hh0 = f2bf(h0), hh1 = f2bf(h1);
    int swz = rr & 15;
    int cw2 = cw + 64;
    int off0 = rr * HH + (((cw >> 3) ^ swz) * 8) + (cw & 7);
    int off1 = rr * HH + (((cw2 >> 3) ^ swz) * 8) + (cw2 & 7);
    Ahi[off0] = hh0;
    Alo[off0] = f2bf(h0 - bf2f(hh0));
    Ahi[off1] = hh1;
    Alo[off1] = f2bf(h1 - bf2f(hh1));
  }
}

// ---------------- fused layer: edge-parallel agg + conv MLP ----------------------
__global__ __launch_bounds__(256, 4) void layer_kernel(
    const float* __restrict__ x,
    const float* __restrict__ ee,
    const int* __restrict__ off,
    const int4* __restrict__ csr_esd,
    const float4* __restrict__ emask_s,
    const float* __restrict__ epsp, int layer,
    const unsigned short* __restrict__ w1hi, const unsigned short* __restrict__ w1lo,
    const float* __restrict__ b1,
    const unsigned short* __restrict__ w2hi, const unsigned short* __restrict__ w2lo,
    const float* __restrict__ b2,
    float* __restrict__ out) {
  __shared__ __align__(16) unsigned short AB[2 * 64 * HH];  // 32 KB (f32 acc overlay)
  unsigned short* Ahi = AB;
  unsigned short* Alo = AB + 64 * HH;
  int tid = threadIdx.x;
  int lane = tid & 63, wq = tid >> 6;
  int ln = lane & 15, quad = lane >> 4;
  int n0 = blockIdx.x * 16;

  agg_phase(x, ee, off, csr_esd, emask_s, 1.0f + epsp[layer], n0, AB, tid);

  bs8 w1h[4][2], w1l[4][2];
  loadW(w1hi, w1lo, w1h, w1l, ln, quad, wq);
  __syncthreads();  // A tile staged

  f32x4 acc[4][2];
  zacc(acc);
  gemm3(Ahi, Alo, w1h, w1l, acc, ln, quad);
  __syncthreads();  // GEMM1 LDS reads done

  bs8 w2h[4][2], w2l[4][2];
  loadW(w2hi, w2lo, w2h, w2l, ln, quad, wq);
  tstage(Ahi, Alo, b1, acc, ln, quad, wq);
  __syncthreads();  // t staged

  zacc(acc);
  gemm3(Ahi, Alo, w2h, w2l, acc, ln, quad);

#pragma unroll
  for (int nt = 0; nt < 2; ++nt) {
    int col = (wq * 2 + nt) * 16 + ln;
    float bb = b2[col];
#pragma unroll
    for (int mt = 0; mt < 4; ++mt)
#pragma unroll
      for (int r = 0; r < 4; ++r) {
        float o = gelu_f(acc[mt][nt][r] + bb);
        out[((size_t)mt * NN + n0 + quad * 4 + r) * HH + col] = o;
      }
  }
}

// ---------------- final MLP + fused masked-sum pooling (R7 proven form) ----------
__global__ __launch_bounds__(256, 2) void mlp_pool_kernel(
    const float* __restrict__ in,
    const unsigned short* __restrict__ w1hi, const unsigned short* __restrict__ w1lo,
    const float* __restrict__ b1,
    const unsigned short* __restrict__ w2hi, const unsigned short* __restrict__ w2lo,
    const float* __restrict__ b2,
    const float* __restrict__ nmask, const int* __restrict__ batch,
    float* __restrict__ num) {
  __shared__ __align__(16) unsigned short AB[128 * LDSA];
  __shared__ int kk[64];
  unsigned short* Ahi = AB;
  unsigned short* Alo = AB + 64 * LDSA;
  int tid = threadIdx.x;
  int row0 = blockIdx.x * 64;
  int lane = tid & 63, wq = tid >> 6;
  int ln = lane & 15, quad = lane >> 4;

  bs8 b1h[4][2], b1l[4][2];
  loadW(w1hi, w1lo, b1h, b1l, ln, quad, wq);
#pragma unroll
  for (int i = 0; i < 8; ++i) {
    int idx = tid + i * 256;
    int r = idx >> 5, cc4 = idx & 31;
    f32x4 vv = __builtin_nontemporal_load(
        (const f32x4*)(in + (size_t)(row0 + r) * HH + cc4 * 4));
    unsigned short h0 = f2bf(vv[0]), h1 = f2bf(vv[1]), h2 = f2bf(vv[2]), h3 = f2bf(vv[3]);
    ushort4 hv; hv.x = h0; hv.y = h1; hv.z = h2; hv.w = h3;
    ushort4 lv;
    lv.x = f2bf(vv[0] - bf2f(h0)); lv.y = f2bf(vv[1] - bf2f(h1));
    lv.z = f2bf(vv[2] - bf2f(h2)); lv.w = f2bf(vv[3] - bf2f(h3));
    *(ushort4*)(Ahi + r * LDSA + cc4 * 4) = hv;
    *(ushort4*)(Alo + r * LDSA + cc4 * 4) = lv;
  }
  if (tid < 64) {
    int gr = row0 + tid;
    int c = gr / NN;
    int n = gr - c * NN;
    kk[tid] = (c << 6) | batch[n];
  }
  __syncthreads();  // B1

  f32x4 acc[4][2];
  zacc(acc);
#pragma unroll
  for (int ks = 0; ks < 4; ++ks) {
    bs8 ah[4], al[4];
#pragma unroll
    for (int mt = 0; mt < 4; ++mt) {
      ah[mt] = *(const bs8*)(Ahi + (mt * 16 + ln) * LDSA + ks * 32 + quad * 8);
      al[mt] = *(const bs8*)(Alo + (mt * 16 + ln) * LDSA + ks * 32 + quad * 8);
    }
#pragma unroll
    for (int nt = 0; nt < 2; ++nt)
#pragma unroll
      for (int mt = 0; mt < 4; ++mt) {
        acc[mt][nt] = __builtin_amdgcn_mfma_f32_16x16x32_bf16(al[mt], b1h[ks][nt], acc[mt][nt], 0, 0, 0);
        acc[mt][nt] = __builtin_amdgcn_mfma_f32_16x16x32_bf16(ah[mt], b1l[ks][nt], acc[mt][nt], 0, 0, 0);
        acc[mt][nt] = __builtin_amdgcn_mfma_f32_16x16x32_bf16(ah[mt], b1h[ks][nt], acc[mt][nt], 0, 0, 0);
      }
  }
  __syncthreads();  // B2

  bs8 b2h[4][2], b2l[4][2];
  loadW(w2hi, w2lo, b2h, b2l, ln, quad, wq);
#pragma unroll
  for (int nt = 0; nt < 2; ++nt) {
    int col = (wq * 2 + nt) * 16 + ln;
    float bb = b1[col];
#pragma unroll
    for (int mt = 0; mt < 4; ++mt)
#pragma unroll
      for (int r = 0; r < 4; ++r) {
        float tv = gelu_f(acc[mt][nt][r] + bb);
        unsigned short th = f2bf(tv);
        int rr = mt * 16 + quad * 4 + r;
        Ahi[rr * LDSA + col] = th;
        Alo[rr * LDSA + col] = f2bf(tv - bf2f(th));
      }
  }
  __syncthreads();  // B3

  zacc(acc);
#pragma unroll
  for (int ks = 0; ks < 4; ++ks) {
    bs8 ah[4], al[4];
#pragma unroll
    for (int mt = 0; mt < 4; ++mt) {
      ah[mt] = *(const bs8*)(Ahi + (mt * 16 + ln) * LDSA + ks * 32 + quad * 8);
      al[mt] = *(const bs8*)(Alo + (mt * 16 + ln) * LDSA + ks * 32 + quad * 8);
    }
#pragma unroll
    for (int nt = 0; nt < 2; ++nt)
#pragma unroll
      for (int mt = 0; mt < 4; ++mt) {
        acc[mt][nt] = __builtin_amdgcn_mfma_f32_16x16x32_bf16(al[mt], b2h[ks][nt], acc[mt][nt], 0, 0, 0);
        acc[mt][nt] = __builtin_amdgcn_mfma_f32_16x16x32_bf16(ah[mt], b2l[ks][nt], acc[mt][nt], 0, 0, 0);
        acc[mt][nt] = __builtin_amdgcn_mfma_f32_16x16x32_bf16(ah[mt], b2h[ks][nt], acc[mt][nt], 0, 0, 0);
      }
  }
  __syncthreads();  // B4
  float* Tf = (float*)AB;
#pragma unroll
  for (int nt = 0; nt < 2; ++nt) {
    int col = (wq * 2 + nt) * 16 + ln;
    float bb = b2[col];
#pragma unroll
    for (int mt = 0; mt < 4; ++mt)
#pragma unroll
      for (int r = 0; r < 4; ++r) {
        int rl = mt * 16 + quad * 4 + r;
        int gr = row0 + rl;
        Tf[rl * LDSF + col] = (acc[mt][nt][r] + bb) * nmask[gr];
      }
  }
  __syncthreads();  // B5
  if (tid < 128) {
    int col = tid;
    float a2 = 0.f;
    int cur = kk[0];
    for (int r = 0; r < 64; ++r) {
      int k2 = kk[r];
      if (k2 != cur) {
        atomicAdd(&num[((size_t)(cur & 63) * CC + (cur >> 6)) * HH + col], a2);
        a2 = 0.f;
        cur = k2;
      }
      a2 += Tf[r * LDSF + col];
    }
    atomicAdd(&num[((size_t)(cur & 63) * CC + (cur >> 6)) * HH + col], a2);
  }
}

// ---------------- pool finalize ----------------
__global__ __launch_bounds__(256) void pool_finalize_kernel(const float* __restrict__ num,
                                                            const int* __restrict__ batch,
                                                            const float* __restrict__ nmask,
                                                            float* __restrict__ outp) {
  int g = blockIdx.x >> 2, c = blockIdx.x & 3;
  int lo = 0, hi = NN;
  while (lo < hi) { int m = (lo + hi) >> 1; if (batch[m] < g) lo = m + 1; else hi = m; }
  int start = lo;
  hi = NN;
  while (lo < hi) { int m = (lo + hi) >> 1; if (batch[m] < g + 1) lo = m + 1; else hi = m; }
  int end = lo;
  int tid = threadIdx.x;
  float d = 0.f;
  for (int n = start + tid; n < end; n += 256) d += nmask[c * NN + n];
#pragma unroll
  for (int k = 1; k < 64; k <<= 1) d += __shfl_xor(d, k);
  __shared__ float ws4[4];
  if ((tid & 63) == 0) ws4[tid >> 6] = d;
  __syncthreads();
  float den = ws4[0] + ws4[1] + ws4[2] + ws4[3] + 1e-7f;
  if (tid < 128) {
    int idx = blockIdx.x * 128 + tid;
    outp[idx] = num[idx] / den;
  }
}

extern "C" void kernel_launch(void* const* d_in, const int* in_sizes, int n_in,
                              void* d_out, int out_size, void* d_ws, size_t ws_size,
                              hipStream_t stream) {
  const float* x_in  = (const float*)d_in[0];
  const int*   batch = (const int*)d_in[1];
  const int*   eidx  = (const int*)d_in[2];
  const float* eattr = (const float*)d_in[3];
  const float* nmask = (const float*)d_in[4];
  const float* emask = (const float*)d_in[5];
  const float* Wbe   = (const float*)d_in[6];
  const float* bbe   = (const float*)d_in[7];
  const float* epsp  = (const float*)d_in[8];
  const float* W1    = (const float*)d_in[9];
  const float* b1    = (const float*)d_in[10];
  const float* W2    = (const float*)d_in[11];
  const float* b2    = (const float*)d_in[12];
  const float* Wm1   = (const float*)d_in[13];
  const float* bm1   = (const float*)d_in[14];
  const float* Wm2   = (const float*)d_in[15];
  const float* bm2   = (const float*)d_in[16];
  float* outp = (float*)d_out;

  const int* srcp = eidx;
  const int* dstp = eidx + EN;

  char* ws = (char*)d_ws;
  float* ee   = (float*)(ws);                  // 102,400,000 B
  float* hbuf = (float*)(ws + 102400000);      // layer-0 output
  float* xbuf = (float*)(ws + 204800000);      // layer-1 output
  int* counts  = (int*)(ws + 307200000);       // 200,000 B
  int* offsets = (int*)(ws + 307400000);       // 200,004 B
  int* cursor  = (int*)(ws + 307600008);       // 200,000 B
  int4* csr_esd = (int4*)(ws + 307800016);     // 3,200,000 B (16-aligned)
  float4* emask_s = (float4*)(ws + 311000016); // 3,200,000 B (16-aligned)
  unsigned short* wts = (unsigned short*)(ws + 314200016);  // 786,432 B
  int* bsums = (int*)ws;                 // overlay: before ee_kernel writes ee
  int* boffs = (int*)(ws + 1024);
  float* num = (float*)ws;               // overlay: after last ee read

  const int NB = (NN + 255) / 256;  // 196

  hipMemsetAsync(counts, 0, NN * sizeof(int), stream);
  count_kernel<<<(EN + 255) / 256, 256, 0, stream>>>(dstp, counts);
  block_sum_kernel<<<NB, 256, 0, stream>>>(counts, bsums);
  bsum_scan_kernel<<<1, 256, 0, stream>>>(bsums, boffs, NB);
  block_scan_kernel<<<NB, 256, 0, stream>>>(counts, boffs, offsets, cursor);
  fill_kernel<<<(EN + 255) / 256, 256, 0, stream>>>(dstp, srcp, emask, cursor, csr_esd, emask_s);

  prep_w_kernel<<<384, 256, 0, stream>>>(W1, W2, Wm1, Wm2, wts);

  ee_kernel<<<EN / 16, 256, 0, stream>>>(eattr, Wbe, bbe, ee);

  // layer 0 (fused agg+MLP): x_in -> hbuf
  layer_kernel<<<NN / 16, 256, 0, stream>>>(x_in, ee, offsets, csr_esd, emask_s, epsp, 0,
                                            wts + 0, wts + 16384, b1,
                                            wts + 65536, wts + 81920, b2, hbuf);
  // layer 1 (fused agg+MLP): hbuf -> xbuf
  layer_kernel<<<NN / 16, 256, 0, stream>>>(hbuf, ee, offsets, csr_esd, emask_s, epsp, 1,
                                            wts + 32768, wts + 49152, b1 + 128,
                                            wts + 98304, wts + 114688, b2 + 128, xbuf);
  // final node MLP with fused masked-sum pooling
  hipMemsetAsync(num, 0, 131072, stream);
  mlp_pool_kernel<<<(CC * NN) / 64, 256, 0, stream>>>(xbuf, wts + 131072, wts + 147456, bm1,
                                                      wts + 163840, wts + 180224, bm2,
                                                      nmask, batch, num);
  pool_finalize_kernel<<<GG * CC, 256, 0, stream>>>(num, batch, nmask, outp);
}

// Round 10
// 634.883 us; speedup vs baseline: 2.3554x; 2.3554x over previous
//
#include <hip/hip_runtime.h>
#include <math.h>

#define NN 50000
#define EN 200000
#define CC 4
#define HH 128
#define GG 64
#define LDSA 136   // padded stride for pool-variant tile
#define LDSF 132   // f32 stride for fused-pool tile

typedef __attribute__((ext_vector_type(8))) short bs8;
typedef __attribute__((ext_vector_type(4))) float f32x4;
typedef __attribute__((ext_vector_type(2))) float f32x2;

__device__ __forceinline__ unsigned short f2bf(float f) {
  unsigned int u = __float_as_uint(f);
  u += 0x7FFFu + ((u >> 16) & 1u);
  return (unsigned short)(u >> 16);
}
__device__ __forceinline__ float bf2f(unsigned short h) {
  return __uint_as_float(((unsigned int)h) << 16);
}
// fast erf-GELU: A&S 7.1.26 minimax (|erf err| ~1.5e-7) + hw rcp/exp
__device__ __forceinline__ float gelu_f(float x) {
  float z = fabsf(x) * 0.7071067811865476f;
  float t = __builtin_amdgcn_rcpf(fmaf(0.3275911f, z, 1.0f));
  float poly = t * fmaf(t, fmaf(t, fmaf(t, fmaf(t, 1.061405429f, -1.453152027f),
                                        1.421413741f), -0.284496736f), 0.254829592f);
  float e = fmaf(-poly, __expf(-z * z), 1.0f);
  return 0.5f * x * (1.0f + copysignf(e, x));
}
// 2*gelu(x) — caller pre-folds the 0.5 into the edge mask
__device__ __forceinline__ float gelu2_f(float x) {
  float z = fabsf(x) * 0.7071067811865476f;
  float t = __builtin_amdgcn_rcpf(fmaf(0.3275911f, z, 1.0f));
  float poly = t * fmaf(t, fmaf(t, fmaf(t, fmaf(t, 1.061405429f, -1.453152027f),
                                        1.421413741f), -0.284496736f), 0.254829592f);
  float e = fmaf(-poly, __expf(-z * z), 1.0f);
  return x * (1.0f + copysignf(e, x));
}

// ---------------- CSR build ----------------
__global__ __launch_bounds__(256) void count_kernel(const int* __restrict__ dst,
                                                    int* __restrict__ counts) {
  int e = blockIdx.x * 256 + threadIdx.x;
  if (e < EN) atomicAdd(&counts[dst[e]], 1);
}

__global__ __launch_bounds__(256) void block_sum_kernel(const int* __restrict__ counts,
                                                        int* __restrict__ bsums) {
  int tid = threadIdx.x;
  int i = blockIdx.x * 256 + tid;
  int v = (i < NN) ? counts[i] : 0;
#pragma unroll
  for (int d = 1; d < 64; d <<= 1) v += __shfl_xor(v, d);
  __shared__ int ws4[4];
  if ((tid & 63) == 0) ws4[tid >> 6] = v;
  __syncthreads();
  if (tid == 0) bsums[blockIdx.x] = ws4[0] + ws4[1] + ws4[2] + ws4[3];
}

__global__ __launch_bounds__(256) void bsum_scan_kernel(const int* __restrict__ bsums,
                                                        int* __restrict__ boffs, int nb) {
  int tid = threadIdx.x, lane = tid & 63, wv = tid >> 6;
  int v = (tid < nb) ? bsums[tid] : 0;
  int s = v;
#pragma unroll
  for (int d = 1; d < 64; d <<= 1) { int t = __shfl_up(s, d); if (lane >= d) s += t; }
  __shared__ int wsum[4];
  if (lane == 63) wsum[wv] = s;
  __syncthreads();
  int pre = 0;
  for (int j = 0; j < wv; ++j) pre += wsum[j];
  if (tid < nb) boffs[tid] = pre + s - v;
}

__global__ __launch_bounds__(256) void block_scan_kernel(const int* __restrict__ counts,
                                                         const int* __restrict__ boffs,
                                                         int* __restrict__ offsets,
                                                         int* __restrict__ cursor) {
  int tid = threadIdx.x, lane = tid & 63, wv = tid >> 6;
  int i = blockIdx.x * 256 + tid;
  int v = (i < NN) ? counts[i] : 0;
  int s = v;
#pragma unroll
  for (int d = 1; d < 64; d <<= 1) { int t = __shfl_up(s, d); if (lane >= d) s += t; }
  __shared__ int wsum[4];
  if (lane == 63) wsum[wv] = s;
  __syncthreads();
  int pre = boffs[blockIdx.x];
  for (int j = 0; j < wv; ++j) pre += wsum[j];
  if (i < NN) { int e = pre + s - v; offsets[i] = e; cursor[i] = e; }
  if (i == 0) offsets[NN] = EN;
}

// fill: CSR-ordered side arrays — src (4B), emask row (16B), eattr row (64B).
// agg then has ZERO random side-streams: only the x[src] gather is irregular.
__global__ __launch_bounds__(256) void fill_kernel(const int* __restrict__ dst,
                                                   const int* __restrict__ src,
                                                   const float* __restrict__ emask,
                                                   const float* __restrict__ eattr,
                                                   int* __restrict__ cursor,
                                                   int* __restrict__ csr_s,
                                                   float4* __restrict__ emask_s,
                                                   float4* __restrict__ eattr_s) {
  int e = blockIdx.x * 256 + threadIdx.x;
  if (e < EN) {
    int s = src[e];
    float m0 = emask[e];
    float m1 = emask[EN + e];
    float m2 = emask[2 * EN + e];
    float m3 = emask[3 * EN + e];
    const float4* ea = (const float4*)(eattr + (size_t)e * 16);
    float4 a0 = ea[0], a1 = ea[1], a2 = ea[2], a3 = ea[3];
    int pos = atomicAdd(&cursor[dst[e]], 1);
    csr_s[pos] = s;
    emask_s[pos] = make_float4(m0, m1, m2, m3);
    eattr_s[(size_t)pos * 4 + 0] = a0;
    eattr_s[(size_t)pos * 4 + 1] = a1;
    eattr_s[(size_t)pos * 4 + 2] = a2;
    eattr_s[(size_t)pos * 4 + 3] = a3;
  }
}

// ---------------- weight prep: transpose + hi/lo bf16 split ----------------------
__global__ __launch_bounds__(256) void prep_w_kernel(const float* __restrict__ W1,
                                                     const float* __restrict__ W2,
                                                     const float* __restrict__ Wm1,
                                                     const float* __restrict__ Wm2,
                                                     unsigned short* __restrict__ wts) {
  int m = blockIdx.x >> 6;
  int idx = (blockIdx.x & 63) * 256 + threadIdx.x;  // 0..16383
  const float* src = (m == 0) ? W1 : (m == 1) ? W1 + 16384 : (m == 2) ? W2
                     : (m == 3) ? W2 + 16384 : (m == 4) ? Wm1 : Wm2;
  unsigned short* dhi = wts + m * 32768;
  unsigned short* dlo = dhi + 16384;
  int n = idx >> 7, k = idx & 127;
  float v = src[k * HH + n];  // src [k][n] -> dst [n][k]
  unsigned short hi = f2bf(v);
  dhi[n * HH + k] = hi;
  dlo[n * HH + k] = f2bf(v - bf2f(hi));
}

// ---------------- MLP helpers ----------------------------------------------------
__device__ __forceinline__ void loadW(const unsigned short* __restrict__ whi,
                                      const unsigned short* __restrict__ wlo,
                                      bs8 (&bh)[4][2], bs8 (&bl)[4][2],
                                      int ln, int quad, int wq) {
#pragma unroll
  for (int ks = 0; ks < 4; ++ks)
#pragma unroll
    for (int nt = 0; nt < 2; ++nt) {
      int wrow = ((wq * 2 + nt) * 16 + ln) * HH + ks * 32 + quad * 8;
      bh[ks][nt] = *(const bs8*)(whi + wrow);
      bl[ks][nt] = *(const bs8*)(wlo + wrow);
    }
}
__device__ __forceinline__ void zacc(f32x4 (&acc)[4][2]) {
#pragma unroll
  for (int mt = 0; mt < 4; ++mt)
#pragma unroll
    for (int nt = 0; nt < 2; ++nt)
#pragma unroll
      for (int r = 0; r < 4; ++r) acc[mt][nt][r] = 0.f;
}
// 3-term GEMM over XOR-swizzled 64xHH LDS tile with preloaded W frags
__device__ __forceinline__ void gemm3(const unsigned short* Ahi, const unsigned short* Alo,
                                      const bs8 (&bh)[4][2], const bs8 (&bl)[4][2],
                                      f32x4 (&acc)[4][2], int ln, int quad) {
#pragma unroll
  for (int ks = 0; ks < 4; ++ks) {
    bs8 ah[4], al[4];
    int sb = ((ks * 4 + quad) ^ ln) * 8;
#pragma unroll
    for (int mt = 0; mt < 4; ++mt) {
      ah[mt] = *(const bs8*)(Ahi + (mt * 16 + ln) * HH + sb);
      al[mt] = *(const bs8*)(Alo + (mt * 16 + ln) * HH + sb);
    }
#pragma unroll
    for (int nt = 0; nt < 2; ++nt)
#pragma unroll
      for (int mt = 0; mt < 4; ++mt) {
        acc[mt][nt] = __builtin_amdgcn_mfma_f32_16x16x32_bf16(al[mt], bh[ks][nt], acc[mt][nt], 0, 0, 0);
        acc[mt][nt] = __builtin_amdgcn_mfma_f32_16x16x32_bf16(ah[mt], bl[ks][nt], acc[mt][nt], 0, 0, 0);
        acc[mt][nt] = __builtin_amdgcn_mfma_f32_16x16x32_bf16(ah[mt], bh[ks][nt], acc[mt][nt], 0, 0, 0);
      }
  }
}
// t = gelu(acc+b) -> swizzled LDS hi/lo
__device__ __forceinline__ void tstage(unsigned short* Ahi, unsigned short* Alo,
                                       const float* __restrict__ bv, f32x4 (&acc)[4][2],
                                       int ln, int quad, int wq) {
#pragma unroll
  for (int nt = 0; nt < 2; ++nt) {
    int col = (wq * 2 + nt) * 16 + ln;
    int cb = col >> 3, co = col & 7;
    float bb = bv[col];
#pragma unroll
    for (int mt = 0; mt < 4; ++mt)
#pragma unroll
      for (int r = 0; r < 4; ++r) {
        float tv = gelu_f(acc[mt][nt][r] + bb);
        unsigned short th = f2bf(tv);
        int rr = mt * 16 + quad * 4 + r;
        int sof = rr * HH + (cb ^ (rr & 15)) * 8 + co;
        Ahi[sof] = th;
        Alo[sof] = f2bf(tv - bf2f(th));
      }
  }
}

// ee for one edge from its eattr row (wave-uniform regs) and per-lane W_be columns
__device__ __forceinline__ float2 ee_from_ea(const f32x4& a0, const f32x4& a1,
                                             const f32x4& a2, const f32x4& a3,
                                             const float (&w0a)[16], const float (&w1a)[16],
                                             float bb0, float bb1) {
  float e0 = bb0, e1 = bb1;
#pragma unroll
  for (int d = 0; d < 4; ++d) { e0 = fmaf(a0[d], w0a[d], e0);      e1 = fmaf(a0[d], w1a[d], e1); }
#pragma unroll
  for (int d = 0; d < 4; ++d) { e0 = fmaf(a1[d], w0a[4 + d], e0);  e1 = fmaf(a1[d], w1a[4 + d], e1); }
#pragma unroll
  for (int d = 0; d < 4; ++d) { e0 = fmaf(a2[d], w0a[8 + d], e0);  e1 = fmaf(a2[d], w1a[8 + d], e1); }
#pragma unroll
  for (int d = 0; d < 4; ++d) { e0 = fmaf(a3[d], w0a[12 + d], e0); e1 = fmaf(a3[d], w1a[12 + d], e1); }
  return make_float2(e0, e1);
}

// ---- agg phase: node-per-wave (R7-proven register pipeline, depth 2), with the
// bond encoding recomputed in-register: W_be columns live in 32 VGPRs, the edge's
// eattr row (64B, CSR-ordered -> sequential wave-uniform broadcast) arrives during
// the previous edge's GELU block, then 32 FMAs produce ee. Kills the 512B/edge
// random ee stream AND the ee_kernel AND halves the L3 working set.
__device__ __forceinline__ void agg_phase(const float* __restrict__ x,
                                          const float* __restrict__ eattr_s,
                                          const int* __restrict__ off,
                                          const int* __restrict__ csr_s,
                                          const float4* __restrict__ emask_s,
                                          const float* __restrict__ Wbe,
                                          const float* __restrict__ bbe,
                                          float ep, int n0,
                                          unsigned short* Ahi, unsigned short* Alo,
                                          int lane, int wq) {
  int c2 = lane * 2;
  int blk = lane >> 2;
  int wo = (lane & 3) * 2;
  float w0a[16], w1a[16];
#pragma unroll
  for (int d = 0; d < 16; ++d) {
    float2 wv = *(const float2*)(Wbe + d * HH + c2);
    w0a[d] = wv.x; w1a[d] = wv.y;
  }
  float2 bbv = *(const float2*)(bbe + c2);
  float bb0 = bbv.x, bb1 = bbv.y;

  for (int j = 0; j < 4; ++j) {
    int nn = wq * 4 + j;
    int v = n0 + nn;
    float2 acc[CC];
#pragma unroll
    for (int c = 0; c < CC; ++c) { acc[c].x = 0.f; acc[c].y = 0.f; }
    int beg = off[v], end = off[v + 1];

    float2 eeC; float2 xC[CC]; float emC[CC]; int sN = 0;
    eeC.x = 0.f; eeC.y = 0.f;
#pragma unroll
    for (int c = 0; c < CC; ++c) { xC[c].x = 0.f; xC[c].y = 0.f; emC[c] = 0.f; }

    if (beg < end) {
      int s0 = csr_s[beg];
      const f32x4* ear = (const f32x4*)(eattr_s + (size_t)beg * 16);
      f32x4 a0 = ear[0], a1 = ear[1], a2 = ear[2], a3 = ear[3];
#pragma unroll
      for (int c = 0; c < CC; ++c)
        xC[c] = *(const float2*)(x + ((size_t)c * NN + s0) * HH + c2);
      float4 m = emask_s[beg];
      emC[0] = 0.5f * m.x; emC[1] = 0.5f * m.y; emC[2] = 0.5f * m.z; emC[3] = 0.5f * m.w;
      eeC = ee_from_ea(a0, a1, a2, a3, w0a, w1a, bb0, bb1);
      if (beg + 1 < end) sN = csr_s[beg + 1];
    }

    for (int t = beg; t < end; ++t) {
      float2 xB[CC]; float emB[CC]; int sNN = 0;
      f32x4 a0 = 0.f, a1 = 0.f, a2 = 0.f, a3 = 0.f;
      bool has = (t + 1 < end);
      if (has) {
        const f32x4* ear = (const f32x4*)(eattr_s + (size_t)(t + 1) * 16);
        a0 = ear[0]; a1 = ear[1]; a2 = ear[2]; a3 = ear[3];
#pragma unroll
        for (int c = 0; c < CC; ++c)
          xB[c] = *(const float2*)(x + ((size_t)c * NN + sN) * HH + c2);
        float4 m = emask_s[t + 1];
        emB[0] = 0.5f * m.x; emB[1] = 0.5f * m.y; emB[2] = 0.5f * m.z; emB[3] = 0.5f * m.w;
        if (t + 2 < end) sNN = csr_s[t + 2];
      } else {
#pragma unroll
        for (int c = 0; c < CC; ++c) { xB[c].x = 0.f; xB[c].y = 0.f; emB[c] = 0.f; }
      }
      // compute edge t (em carries the 0.5 of gelu)
#pragma unroll
      for (int c = 0; c < CC; ++c) {
        acc[c].x += gelu2_f(xC[c].x + eeC.x) * emC[c];
        acc[c].y += gelu2_f(xC[c].y + eeC.y) * emC[c];
      }
      // ee for edge t+1 — the Ea load latency hid under the GELU block above
      eeC = ee_from_ea(a0, a1, a2, a3, w0a, w1a, bb0, bb1);
#pragma unroll
      for (int c = 0; c < CC; ++c) { xC[c] = xB[c]; emC[c] = emB[c]; }
      sN = sNN;
    }

    // h = (1+eps)*x_self + acc -> bf16 hi/lo into swizzled tile row rr = c*16+nn
#pragma unroll
    for (int c = 0; c < CC; ++c) {
      float2 xs = *(const float2*)(x + ((size_t)c * NN + v) * HH + c2);
      float o0 = fmaf(ep, xs.x, acc[c].x);
      float o1 = fmaf(ep, xs.y, acc[c].y);
      int rr = c * 16 + nn;
      int base = rr * HH + ((blk ^ (rr & 15)) * 8) + wo;
      unsigned short h0 = f2bf(o0), h1 = f2bf(o1);
      ushort2 hv; hv.x = h0; hv.y = h1;
      ushort2 lv; lv.x = f2bf(o0 - bf2f(h0)); lv.y = f2bf(o1 - bf2f(h1));
      *(ushort2*)(Ahi + base) = hv;
      *(ushort2*)(Alo + base) = lv;
    }
  }
}

// ---------------- fused layer: agg (ee-recompute) + conv MLP ---------------------
__global__ __launch_bounds__(256, 4) void layer_kernel(
    const float* __restrict__ x,
    const float* __restrict__ eattr_s,
    const int* __restrict__ off,
    const int* __restrict__ csr_s,
    const float4* __restrict__ emask_s,
    const float* __restrict__ Wbe, const float* __restrict__ bbe,
    const float* __restrict__ epsp, int layer,
    const unsigned short* __restrict__ w1hi, const unsigned short* __restrict__ w1lo,
    const float* __restrict__ b1,
    const unsigned short* __restrict__ w2hi, const unsigned short* __restrict__ w2lo,
    const float* __restrict__ b2,
    float* __restrict__ out) {
  __shared__ __align__(16) unsigned short AB[2 * 64 * HH];  // 32 KB
  unsigned short* Ahi = AB;
  unsigned short* Alo = AB + 64 * HH;
  int tid = threadIdx.x;
  int lane = tid & 63, wq = tid >> 6;
  int ln = lane & 15, quad = lane >> 4;
  int n0 = blockIdx.x * 16;

  agg_phase(x, eattr_s, off, csr_s, emask_s, Wbe, bbe,
            1.0f + epsp[layer], n0, Ahi, Alo, lane, wq);

  bs8 w1h[4][2], w1l[4][2];
  loadW(w1hi, w1lo, w1h, w1l, ln, quad, wq);
  __syncthreads();  // A tile staged

  f32x4 acc[4][2];
  zacc(acc);
  gemm3(Ahi, Alo, w1h, w1l, acc, ln, quad);
  __syncthreads();  // GEMM1 LDS reads done

  bs8 w2h[4][2], w2l[4][2];
  loadW(w2hi, w2lo, w2h, w2l, ln, quad, wq);
  tstage(Ahi, Alo, b1, acc, ln, quad, wq);
  __syncthreads();  // t staged

  zacc(acc);
  gemm3(Ahi, Alo, w2h, w2l, acc, ln, quad);

#pragma unroll
  for (int nt = 0; nt < 2; ++nt) {
    int col = (wq * 2 + nt) * 16 + ln;
    float bb = b2[col];
#pragma unroll
    for (int mt = 0; mt < 4; ++mt)
#pragma unroll
      for (int r = 0; r < 4; ++r) {
        float o = gelu_f(acc[mt][nt][r] + bb);
        out[((size_t)mt * NN + n0 + quad * 4 + r) * HH + col] = o;
      }
  }
}

// ---------------- final MLP + fused masked-sum pooling (proven form) -------------
__global__ __launch_bounds__(256, 2) void mlp_pool_kernel(
    const float* __restrict__ in,
    const unsigned short* __restrict__ w1hi, const unsigned short* __restrict__ w1lo,
    const float* __restrict__ b1,
    const unsigned short* __restrict__ w2hi, const unsigned short* __restrict__ w2lo,
    const float* __restrict__ b2,
    const float* __restrict__ nmask, const int* __restrict__ batch,
    float* __restrict__ num) {
  __shared__ __align__(16) unsigned short AB[128 * LDSA];
  __shared__ int kk[64];
  unsigned short* Ahi = AB;
  unsigned short* Alo = AB + 64 * LDSA;
  int tid = threadIdx.x;
  int row0 = blockIdx.x * 64;
  int lane = tid & 63, wq = tid >> 6;
  int ln = lane & 15, quad = lane >> 4;

  bs8 b1h[4][2], b1l[4][2];
  loadW(w1hi, w1lo, b1h, b1l, ln, quad, wq);
#pragma unroll
  for (int i = 0; i < 8; ++i) {
    int idx = tid + i * 256;
    int r = idx >> 5, cc4 = idx & 31;
    f32x4 vv = __builtin_nontemporal_load(
        (const f32x4*)(in + (size_t)(row0 + r) * HH + cc4 * 4));
    unsigned short h0 = f2bf(vv[0]), h1 = f2bf(vv[1]), h2 = f2bf(vv[2]), h3 = f2bf(vv[3]);
    ushort4 hv; hv.x = h0; hv.y = h1; hv.z = h2; hv.w = h3;
    ushort4 lv;
    lv.x = f2bf(vv[0] - bf2f(h0)); lv.y = f2bf(vv[1] - bf2f(h1));
    lv.z = f2bf(vv[2] - bf2f(h2)); lv.w = f2bf(vv[3] - bf2f(h3));
    *(ushort4*)(Ahi + r * LDSA + cc4 * 4) = hv;
    *(ushort4*)(Alo + r * LDSA + cc4 * 4) = lv;
  }
  if (tid < 64) {
    int gr = row0 + tid;
    int c = gr / NN;
    int n = gr - c * NN;
    kk[tid] = (c << 6) | batch[n];
  }
  __syncthreads();  // B1

  f32x4 acc[4][2];
  zacc(acc);
#pragma unroll
  for (int ks = 0; ks < 4; ++ks) {
    bs8 ah[4], al[4];
#pragma unroll
    for (int mt = 0; mt < 4; ++mt) {
      ah[mt] = *(const bs8*)(Ahi + (mt * 16 + ln) * LDSA + ks * 32 + quad * 8);
      al[mt] = *(const bs8*)(Alo + (mt * 16 + ln) * LDSA + ks * 32 + quad * 8);
    }
#pragma unroll
    for (int nt = 0; nt < 2; ++nt)
#pragma unroll
      for (int mt = 0; mt < 4; ++mt) {
        acc[mt][nt] = __builtin_amdgcn_mfma_f32_16x16x32_bf16(al[mt], b1h[ks][nt], acc[mt][nt], 0, 0, 0);
        acc[mt][nt] = __builtin_amdgcn_mfma_f32_16x16x32_bf16(ah[mt], b1l[ks][nt], acc[mt][nt], 0, 0, 0);
        acc[mt][nt] = __builtin_amdgcn_mfma_f32_16x16x32_bf16(ah[mt], b1h[ks][nt], acc[mt][nt], 0, 0, 0);
      }
  }
  __syncthreads();  // B2

  bs8 b2h[4][2], b2l[4][2];
  loadW(w2hi, w2lo, b2h, b2l, ln, quad, wq);
#pragma unroll
  for (int nt = 0; nt < 2; ++nt) {
    int col = (wq * 2 + nt) * 16 + ln;
    float bb = b1[col];
#pragma unroll
    for (int mt = 0; mt < 4; ++mt)
#pragma unroll
      for (int r = 0; r < 4; ++r) {
        float tv = gelu_f(acc[mt][nt][r] + bb);
        unsigned short th = f2bf(tv);
        int rr = mt * 16 + quad * 4 + r;
        Ahi[rr * LDSA + col] = th;
        Alo[rr * LDSA + col] = f2bf(tv - bf2f(th));
      }
  }
  __syncthreads();  // B3

  zacc(acc);
#pragma unroll
  for (int ks = 0; ks < 4; ++ks) {
    bs8 ah[4], al[4];
#pragma unroll
    for (int mt = 0; mt < 4; ++mt) {
      ah[mt] = *(const bs8*)(Ahi + (mt * 16 + ln) * LDSA + ks * 32 + quad * 8);
      al[mt] = *(const bs8*)(Alo + (mt * 16 + ln) * LDSA + ks * 32 + quad * 8);
    }
#pragma unroll
    for (int nt = 0; nt < 2; ++nt)
#pragma unroll
      for (int mt = 0; mt < 4; ++mt) {
        acc[mt][nt] = __builtin_amdgcn_mfma_f32_16x16x32_bf16(al[mt], b2h[ks][nt], acc[mt][nt], 0, 0, 0);
        acc[mt][nt] = __builtin_amdgcn_mfma_f32_16x16x32_bf16(ah[mt], b2l[ks][nt], acc[mt][nt], 0, 0, 0);
        acc[mt][nt] = __builtin_amdgcn_mfma_f32_16x16x32_bf16(ah[mt], b2h[ks][nt], acc[mt][nt], 0, 0, 0);
      }
  }
  __syncthreads();  // B4
  float* Tf = (float*)AB;
#pragma unroll
  for (int nt = 0; nt < 2; ++nt) {
    int col = (wq * 2 + nt) * 16 + ln;
    float bb = b2[col];
#pragma unroll
    for (int mt = 0; mt < 4; ++mt)
#pragma unroll
      for (int r = 0; r < 4; ++r) {
        int rl = mt * 16 + quad * 4 + r;
        int gr = row0 + rl;
        Tf[rl * LDSF + col] = (acc[mt][nt][r] + bb) * nmask[gr];
      }
  }
  __syncthreads();  // B5
  if (tid < 128) {
    int col = tid;
    float a2 = 0.f;
    int cur = kk[0];
    for (int r = 0; r < 64; ++r) {
      int k2 = kk[r];
      if (k2 != cur) {
        atomicAdd(&num[((size_t)(cur & 63) * CC + (cur >> 6)) * HH + col], a2);
        a2 = 0.f;
        cur = k2;
      }
      a2 += Tf[r * LDSF + col];
    }
    atomicAdd(&num[((size_t)(cur & 63) * CC + (cur >> 6)) * HH + col], a2);
  }
}

// ---------------- pool finalize ----------------
__global__ __launch_bounds__(256) void pool_finalize_kernel(const float* __restrict__ num,
                                                            const int* __restrict__ batch,
                                                            const float* __restrict__ nmask,
                                                            float* __restrict__ outp) {
  int g = blockIdx.x >> 2, c = blockIdx.x & 3;
  int lo = 0, hi = NN;
  while (lo < hi) { int m = (lo + hi) >> 1; if (batch[m] < g) lo = m + 1; else hi = m; }
  int start = lo;
  hi = NN;
  while (lo < hi) { int m = (lo + hi) >> 1; if (batch[m] < g + 1) lo = m + 1; else hi = m; }
  int end = lo;
  int tid = threadIdx.x;
  float d = 0.f;
  for (int n = start + tid; n < end; n += 256) d += nmask[c * NN + n];
#pragma unroll
  for (int k = 1; k < 64; k <<= 1) d += __shfl_xor(d, k);
  __shared__ float ws4[4];
  if ((tid & 63) == 0) ws4[tid >> 6] = d;
  __syncthreads();
  float den = ws4[0] + ws4[1] + ws4[2] + ws4[3] + 1e-7f;
  if (tid < 128) {
    int idx = blockIdx.x * 128 + tid;
    outp[idx] = num[idx] / den;
  }
}

extern "C" void kernel_launch(void* const* d_in, const int* in_sizes, int n_in,
                              void* d_out, int out_size, void* d_ws, size_t ws_size,
                              hipStream_t stream) {
  const float* x_in  = (const float*)d_in[0];
  const int*   batch = (const int*)d_in[1];
  const int*   eidx  = (const int*)d_in[2];
  const float* eattr = (const float*)d_in[3];
  const float* nmask = (const float*)d_in[4];
  const float* emask = (const float*)d_in[5];
  const float* Wbe   = (const float*)d_in[6];
  const float* bbe   = (const float*)d_in[7];
  const float* epsp  = (const float*)d_in[8];
  const float* W1    = (const float*)d_in[9];
  const float* b1    = (const float*)d_in[10];
  const float* W2    = (const float*)d_in[11];
  const float* b2    = (const float*)d_in[12];
  const float* Wm1   = (const float*)d_in[13];
  const float* bm1   = (const float*)d_in[14];
  const float* Wm2   = (const float*)d_in[15];
  const float* bm2   = (const float*)d_in[16];
  float* outp = (float*)d_out;

  const int* srcp = eidx;
  const int* dstp = eidx + EN;

  char* ws = (char*)d_ws;
  float* hbuf = (float*)(ws);                  // 102,400,000 B (layer-0 output)
  float* xbuf = (float*)(ws + 102400000);      // 102,400,000 B (layer-1 output)
  int* counts  = (int*)(ws + 204800000);       // 200,000 B
  int* offsets = (int*)(ws + 205000000);       // 200,004 B
  int* cursor  = (int*)(ws + 205200008);       // 200,000 B
  int* csr_s   = (int*)(ws + 205400008);       // 800,000 B
  float4* emask_s = (float4*)(ws + 206200016); // 3,200,000 B (16-aligned)
  float4* eattr_s = (float4*)(ws + 209400016); // 12,800,000 B (16-aligned)
  unsigned short* wts = (unsigned short*)(ws + 222200016);  // 786,432 B
  int* bsums = (int*)ws;                 // overlay: CSR build precedes hbuf writes
  int* boffs = (int*)(ws + 1024);
  float* num = (float*)ws;               // overlay: after layer1's last hbuf read

  const int NB = (NN + 255) / 256;  // 196

  hipMemsetAsync(counts, 0, NN * sizeof(int), stream);
  count_kernel<<<(EN + 255) / 256, 256, 0, stream>>>(dstp, counts);
  block_sum_kernel<<<NB, 256, 0, stream>>>(counts, bsums);
  bsum_scan_kernel<<<1, 256, 0, stream>>>(bsums, boffs, NB);
  block_scan_kernel<<<NB, 256, 0, stream>>>(counts, boffs, offsets, cursor);
  fill_kernel<<<(EN + 255) / 256, 256, 0, stream>>>(dstp, srcp, emask, eattr,
                                                    cursor, csr_s, emask_s, eattr_s);

  prep_w_kernel<<<384, 256, 0, stream>>>(W1, W2, Wm1, Wm2, wts);

  // layer 0 (fused agg+MLP, ee recomputed in-register): x_in -> hbuf
  layer_kernel<<<NN / 16, 256, 0, stream>>>(x_in, (const float*)eattr_s, offsets, csr_s,
                                            emask_s, Wbe, bbe, epsp, 0,
                                            wts + 0, wts + 16384, b1,
                                            wts + 65536, wts + 81920, b2, hbuf);
  // layer 1: hbuf -> xbuf
  layer_kernel<<<NN / 16, 256, 0, stream>>>(hbuf, (const float*)eattr_s, offsets, csr_s,
                                            emask_s, Wbe, bbe, epsp, 1,
                                            wts + 32768, wts + 49152, b1 + 128,
                                            wts + 98304, wts + 114688, b2 + 128, xbuf);
  // final node MLP with fused masked-sum pooling (num overlays hbuf, free now)
  hipMemsetAsync(num, 0, 131072, stream);
  mlp_pool_kernel<<<(CC * NN) / 64, 256, 0, stream>>>(xbuf, wts + 131072, wts + 147456, bm1,
                                                      wts + 163840, wts + 180224, bm2,
                                                      nmask, batch, num);
  pool_finalize_kernel<<<GG * CC, 256, 0, stream>>>(num, batch, nmask, outp);
}